// Round 2
// baseline (759.233 us; speedup 1.0000x reference)
//
#include <hip/hip_runtime.h>
#include <stdint.h>

typedef unsigned short u16;
typedef unsigned int u32;
typedef __attribute__((ext_vector_type(8))) short bf16x8;
typedef __attribute__((ext_vector_type(4))) float f32x4;

__device__ __forceinline__ float bf2f(u16 u) {
    union { u32 i; float f; } v; v.i = ((u32)u) << 16; return v.f;
}
__device__ __forceinline__ u16 f2bf(float f) {
    union { float f; u32 i; } v; v.f = f;
    u32 x = v.i;
    u32 r = (x + 0x7FFFu + ((x >> 16) & 1u)) >> 16;  // RNE
    return (u16)r;
}

__device__ __forceinline__ void gld_lds16(const void* g, void* l) {
    __builtin_amdgcn_global_load_lds(
        (const __attribute__((address_space(1))) void*)g,
        (__attribute__((address_space(3))) void*)l, 16, 0, 0);
}

// ---------------- f32 -> bf16 row convert (vectorized) ---------------------
__global__ __launch_bounds__(256) void cvt_rows(
    const float* __restrict__ src, u16* __restrict__ dst, size_t total4) {
    size_t i = (size_t)blockIdx.x * 256 + threadIdx.x;  // one float4 per thread
    if (i >= total4) return;
    const float4 v = ((const float4*)src)[i];
    u16 o[4] = {f2bf(v.x), f2bf(v.y), f2bf(v.z), f2bf(v.w)};
    *(unsigned long long*)(dst + i * 4) = *(unsigned long long*)o;
}

// ---------------- transpose+convert: dst_bf16[c][r] = src_f32[r][c] --------
__global__ __launch_bounds__(256) void transpose_cvt(
    const float* __restrict__ src, u16* __restrict__ dst, int R, int C) {
    __shared__ float tile[32][33];
    int c0 = blockIdx.x * 32, r0 = blockIdx.y * 32;
    int tx = threadIdx.x & 31, ty = threadIdx.x >> 5;  // ty 0..7
    for (int rr = ty; rr < 32; rr += 8)
        tile[rr][tx] = src[(size_t)(r0 + rr) * C + c0 + tx];
    __syncthreads();
    for (int rr = ty; rr < 32; rr += 8)
        dst[(size_t)(c0 + rr) * R + r0 + tx] = f2bf(tile[tx][rr]);
}

// ---------------- GEMM: C[M][N] = A[M][K] * Bt[N][K]^T, bf16 inputs --------
// MODE 0: bf16 out, no bias.  MODE 1: f32 out + f32 bias.
// m97 structure: BM=BN=128, BK=32, 4 waves, global_load_lds width 16.
template <int MODE>
__global__ __launch_bounds__(256) void gemm_bt(
    const u16* __restrict__ A, const u16* __restrict__ Bt,
    const float* __restrict__ bias, void* __restrict__ Cv,
    int M, int N, int K) {
    __shared__ u16 As[128 * 32];
    __shared__ u16 Bs[128 * 32];
    int tid = threadIdx.x;
    int wid = tid >> 6, lane = tid & 63;
    int m0 = blockIdx.x * 128, n0 = blockIdx.y * 128;
    int wr = wid >> 1, wc = wid & 1;
    int lr = lane & 15, lk = (lane >> 4) * 8;
    f32x4 acc[4][4] = {};

    for (int k0 = 0; k0 < K; k0 += 32) {
        for (int p = 0; p < 2; ++p) {
            int idx = p * 256 + tid;        // 0..511
            int row = idx >> 2;             // 0..127
            int col = (idx & 3) * 8;
            int gm = m0 + row; if (gm > M - 1) gm = M - 1;  // clamp tail
            gld_lds16(A + (size_t)gm * K + k0 + col, As + idx * 8);
            int gn = n0 + row;              // N multiple of 128
            gld_lds16(Bt + (size_t)gn * K + k0 + col, Bs + idx * 8);
        }
        __syncthreads();
        bf16x8 a[4], b[4];
        for (int mi = 0; mi < 4; ++mi)
            a[mi] = *(const bf16x8*)&As[(wr * 64 + mi * 16 + lr) * 32 + lk];
        for (int ni = 0; ni < 4; ++ni)
            b[ni] = *(const bf16x8*)&Bs[(wc * 64 + ni * 16 + lr) * 32 + lk];
        for (int mi = 0; mi < 4; ++mi)
            for (int ni = 0; ni < 4; ++ni)
                acc[mi][ni] = __builtin_amdgcn_mfma_f32_16x16x32_bf16(
                    a[mi], b[ni], acc[mi][ni], 0, 0, 0);
        __syncthreads();
    }

    int lq = lane >> 4;
    for (int mi = 0; mi < 4; ++mi)
        for (int ni = 0; ni < 4; ++ni) {
            int col = n0 + wc * 64 + ni * 16 + lr;
            float bv = (MODE == 1) ? bias[col] : 0.0f;
            for (int r = 0; r < 4; ++r) {
                int row = m0 + wr * 64 + mi * 16 + lq * 4 + r;
                if (row < M) {
                    if (MODE == 0)
                        ((u16*)Cv)[(size_t)row * N + col] = f2bf(acc[mi][ni][r]);
                    else
                        ((float*)Cv)[(size_t)row * N + col] = acc[mi][ni][r] + bv;
                }
            }
        }
}

// ---------------- bos row: attn_out[b*4097][:] = v[b, n=0, :] --------------
__global__ __launch_bounds__(256) void bos_copy(
    const u16* __restrict__ qkv, u16* __restrict__ attn_out) {
    int b = blockIdx.x;
    int c = blockIdx.y * 256 + threadIdx.x;  // 0..1023
    attn_out[(size_t)b * 4097 * 1024 + c] =
        qkv[(size_t)b * 4097 * 3072 + 2048 + c];
}

// ---------------- fused windowed attention + talking-heads -----------------
// one WG (4 waves) per (x, b). qkv rows: t = 0..4096 per batch; q/k/v at
// cols 0/1024/2048. q-token i of tile x: t = 1 + x*16 + i. window j=0 -> bos,
// j=1..80 -> t = 1 + (x*16 - 32 + (j-1)). causal mask: j>i+33 (covers the
// right window edge too since q_pos <= 4095); left edge needs tpos >= 0.
__global__ __launch_bounds__(256) void attn_kernel(
    const u16* __restrict__ qkv, const float* __restrict__ w_th,
    u16* __restrict__ attn_out) {
    __shared__ u16 attn_s[16 * 81 * 18];       // [i][j][h stride 18] bf16 probs
    __shared__ u16 vt[4][64 * 104];            // per-wave V^T [d][j], j pad 96
    __shared__ float wth_s[256];

    int tid = threadIdx.x;
    int wid = tid >> 6, lane = tid & 63;
    int x = blockIdx.x;                        // 0..255
    int b = blockIdx.y;                        // 0..3
    size_t base = (size_t)b * 4097 * 3072;
    int lr = lane & 15;
    int lq = lane >> 4;
    int lk8 = lq * 8;

    wth_s[tid] = w_th[tid];

    // ---- phase 1: per-head QK^T + mask + softmax -> attn_s -----------------
    for (int hh = 0; hh < 4; ++hh) {
        int h = wid * 4 + hh;
        const u16* qp = qkv + base + (size_t)(1 + x * 16 + lr) * 3072 + h * 64;
        bf16x8 aq0 = *(const bf16x8*)(qp + lk8);
        bf16x8 aq1 = *(const bf16x8*)(qp + 32 + lk8);
        f32x4 acc[6];
        for (int jt = 0; jt < 6; ++jt) {
            int j = jt * 16 + lr;
            int tpos = x * 16 - 32 + (j - 1);
            int t = 0;
            if (j != 0 && j <= 80 && tpos >= 0 && tpos < 4096) t = 1 + tpos;
            const u16* kp = qkv + base + (size_t)t * 3072 + 1024 + h * 64;
            bf16x8 bk0 = *(const bf16x8*)(kp + lk8);
            bf16x8 bk1 = *(const bf16x8*)(kp + 32 + lk8);
            f32x4 c = {};
            c = __builtin_amdgcn_mfma_f32_16x16x32_bf16(aq0, bk0, c, 0, 0, 0);
            c = __builtin_amdgcn_mfma_f32_16x16x32_bf16(aq1, bk1, c, 0, 0, 0);
            acc[jt] = c;
        }
        // mask + softmax over j (spread across 16 lanes x 6 tiles)
        float m[4], s[4], p[6][4];
        for (int r = 0; r < 4; ++r) m[r] = -3.0e38f;
        for (int jt = 0; jt < 6; ++jt) {
            int j = jt * 16 + lr;
            int tpos = x * 16 - 32 + (j - 1);
            bool jvalid = (j == 0) || ((j <= 80) && (tpos >= 0));
            for (int r = 0; r < 4; ++r) {
                int i = lq * 4 + r;
                bool keep = jvalid && (j == 0 || j <= i + 33);
                float v = keep ? acc[jt][r] * 0.125f : -3.0e38f;
                p[jt][r] = v;
                m[r] = fmaxf(m[r], v);
            }
        }
        for (int r = 0; r < 4; ++r) {
            float v = m[r];
            v = fmaxf(v, __shfl_xor(v, 1));
            v = fmaxf(v, __shfl_xor(v, 2));
            v = fmaxf(v, __shfl_xor(v, 4));
            v = fmaxf(v, __shfl_xor(v, 8));
            m[r] = v; s[r] = 0.0f;
        }
        for (int jt = 0; jt < 6; ++jt)
            for (int r = 0; r < 4; ++r) {
                float e = __expf(p[jt][r] - m[r]);
                p[jt][r] = e; s[r] += e;
            }
        for (int r = 0; r < 4; ++r) {
            float v = s[r];
            v += __shfl_xor(v, 1); v += __shfl_xor(v, 2);
            v += __shfl_xor(v, 4); v += __shfl_xor(v, 8);
            s[r] = 1.0f / v;
        }
        for (int jt = 0; jt < 6; ++jt) {
            int j = jt * 16 + lr;
            if (j <= 80)
                for (int r = 0; r < 4; ++r) {
                    int i = lq * 4 + r;
                    attn_s[(i * 81 + j) * 18 + h] = f2bf(p[jt][r] * s[r]);
                }
        }
    }
    __syncthreads();

    // ---- phase 2: per-head head-mix (g) + PV MFMA --------------------------
    for (int gg = 0; gg < 4; ++gg) {
        int g = wid * 4 + gg;
        // stage V^T for head g: vt[wid][d=lane][j]
        for (int j = 0; j < 96; ++j) {
            u16 val = 0;
            if (j <= 80) {
                int t = 0;
                int tpos = x * 16 - 32 + (j - 1);
                if (j == 0) t = 0;
                else if (tpos >= 0 && tpos < 4096) t = 1 + tpos;
                val = qkv[base + (size_t)t * 3072 + 2048 + g * 64 + lane];
            }
            vt[wid][lane * 104 + j] = val;
        }
        float wth[16];
        for (int h2 = 0; h2 < 16; ++h2) wth[h2] = wth_s[g * 16 + h2];
        // mix heads into A-frags (row i = lr, k = j)
        bf16x8 pa[3];
        for (int kk = 0; kk < 3; ++kk) {
            bf16x8 av;
            for (int e = 0; e < 8; ++e) {
                int j = kk * 32 + lk8 + e;
                float sum = 0.0f;
                if (j <= 80) {
                    const u16* ap = &attn_s[(lr * 81 + j) * 18];
                    for (int h2 = 0; h2 < 16; ++h2)
                        sum += wth[h2] * bf2f(ap[h2]);
                }
                av[e] = (short)f2bf(sum);
            }
            pa[kk] = av;
        }
        // PV: out[i][d] = sum_j P[i][j] * V[j][d]
        for (int dt = 0; dt < 4; ++dt) {
            f32x4 c = {};
            for (int kk = 0; kk < 3; ++kk) {
                bf16x8 bv = *(const bf16x8*)
                    &vt[wid][(dt * 16 + lr) * 104 + kk * 32 + lk8];
                c = __builtin_amdgcn_mfma_f32_16x16x32_bf16(pa[kk], bv, c, 0, 0, 0);
            }
            int col = g * 64 + dt * 16 + lr;
            for (int r = 0; r < 4; ++r) {
                int i = lq * 4 + r;
                size_t row = (size_t)b * 4097 + 1 + (size_t)x * 16 + i;
                attn_out[row * 1024 + col] = f2bf(c[r]);
            }
        }
    }
}

// ---------------------------------------------------------------------------
extern "C" void kernel_launch(void* const* d_in, const int* in_sizes, int n_in,
                              void* d_out, int out_size, void* d_ws, size_t ws_size,
                              hipStream_t stream) {
    const float* x     = (const float*)d_in[0];  // (4,4097,1024) f32
    const float* w_qkv = (const float*)d_in[1];  // (1024,3072)  f32
    const float* w_out = (const float*)d_in[2];  // (1024,1024)  f32
    const float* b_out = (const float*)d_in[3];  // (1024,)      f32
    const float* w_th  = (const float*)d_in[4];  // (16,16)      f32
    float* out = (float*)d_out;                  // (4,4097,1024) f32

    const int M = 4 * 4097;  // 16388
    u16* qkv      = (u16*)d_ws;                       // M x 3072      bf16
    u16* wqkvT    = qkv + (size_t)M * 3072;           // 3072 x 1024   bf16
    u16* woutT    = wqkvT + (size_t)3072 * 1024;      // 1024 x 1024   bf16
    u16* xb       = woutT + (size_t)1024 * 1024;      // M x 1024      bf16
    u16* attn_out = xb;  // aliases xb: xb dead after GEMM1 (stream-ordered)

    transpose_cvt<<<dim3(96, 32), 256, 0, stream>>>(w_qkv, wqkvT, 1024, 3072);
    transpose_cvt<<<dim3(32, 32), 256, 0, stream>>>(w_out, woutT, 1024, 1024);

    size_t total4 = (size_t)M * 1024 / 4;  // 4,195,328 float4s
    cvt_rows<<<(int)((total4 + 255) / 256), 256, 0, stream>>>(x, xb, total4);

    int mt = (M + 127) / 128;  // 129
    gemm_bt<0><<<dim3(mt, 3072 / 128), 256, 0, stream>>>(
        xb, wqkvT, nullptr, qkv, M, 3072, 1024);

    bos_copy<<<dim3(4, 4), 256, 0, stream>>>(qkv, attn_out);
    attn_kernel<<<dim3(256, 4), 256, 0, stream>>>(qkv, w_th, attn_out);

    gemm_bt<1><<<dim3(mt, 1024 / 128), 256, 0, stream>>>(
        attn_out, woutT, b_out, out, M, 1024, 1024);
}

// Round 5
// 325.891 us; speedup vs baseline: 2.3297x; 2.3297x over previous
//
#include <hip/hip_runtime.h>
#include <stdint.h>

typedef unsigned short u16;
typedef unsigned int u32;
typedef __attribute__((ext_vector_type(8))) short bf16x8;
typedef __attribute__((ext_vector_type(4))) float f32x4;

__device__ __forceinline__ float bf2f(u16 u) {
    union { u32 i; float f; } v; v.i = ((u32)u) << 16; return v.f;
}
__device__ __forceinline__ u16 f2bf(float f) {
    union { float f; u32 i; } v; v.f = f;
    u32 x = v.i;
    u32 r = (x + 0x7FFFu + ((x >> 16) & 1u)) >> 16;  // RNE
    return (u16)r;
}

__device__ __forceinline__ void gld_lds16(const void* g, void* l) {
    __builtin_amdgcn_global_load_lds(
        (const __attribute__((address_space(1))) void*)g,
        (__attribute__((address_space(3))) void*)l, 16, 0, 0);
}

// ---------------- f32 -> bf16 row convert (vectorized) ---------------------
__global__ __launch_bounds__(256) void cvt_rows(
    const float* __restrict__ src, u16* __restrict__ dst, size_t total4) {
    size_t i = (size_t)blockIdx.x * 256 + threadIdx.x;  // one float4 per thread
    if (i >= total4) return;
    const float4 v = ((const float4*)src)[i];
    u16 o[4] = {f2bf(v.x), f2bf(v.y), f2bf(v.z), f2bf(v.w)};
    *(unsigned long long*)(dst + i * 4) = *(unsigned long long*)o;
}

// ---------------- transpose+convert: dst_bf16[c][r] = src_f32[r][c] --------
__global__ __launch_bounds__(256) void transpose_cvt(
    const float* __restrict__ src, u16* __restrict__ dst, int R, int C) {
    __shared__ float tile[32][33];
    int c0 = blockIdx.x * 32, r0 = blockIdx.y * 32;
    int tx = threadIdx.x & 31, ty = threadIdx.x >> 5;  // ty 0..7
    for (int rr = ty; rr < 32; rr += 8)
        tile[rr][tx] = src[(size_t)(r0 + rr) * C + c0 + tx];
    __syncthreads();
    for (int rr = ty; rr < 32; rr += 8)
        dst[(size_t)(c0 + rr) * R + r0 + tx] = f2bf(tile[tx][rr]);
}

// ---------------- GEMM: C[M][N] = A[M][K] * Bt[N][K]^T, bf16 inputs --------
// MODE 0: bf16 out, no bias.  MODE 1: f32 out + f32 bias.
template <int MODE>
__global__ __launch_bounds__(256) void gemm_bt(
    const u16* __restrict__ A, const u16* __restrict__ Bt,
    const float* __restrict__ bias, void* __restrict__ Cv,
    int M, int N, int K) {
    __shared__ u16 As[128 * 32];
    __shared__ u16 Bs[128 * 32];
    int tid = threadIdx.x;
    int wid = tid >> 6, lane = tid & 63;
    int m0 = blockIdx.x * 128, n0 = blockIdx.y * 128;
    int wr = wid >> 1, wc = wid & 1;
    int lr = lane & 15, lk = (lane >> 4) * 8;
    f32x4 acc[4][4] = {};

    for (int k0 = 0; k0 < K; k0 += 32) {
        for (int p = 0; p < 2; ++p) {
            int idx = p * 256 + tid;        // 0..511
            int row = idx >> 2;             // 0..127
            int col = (idx & 3) * 8;
            int gm = m0 + row; if (gm > M - 1) gm = M - 1;  // clamp tail
            gld_lds16(A + (size_t)gm * K + k0 + col, As + idx * 8);
            int gn = n0 + row;              // N multiple of 128
            gld_lds16(Bt + (size_t)gn * K + k0 + col, Bs + idx * 8);
        }
        __syncthreads();
        bf16x8 a[4], b[4];
        for (int mi = 0; mi < 4; ++mi)
            a[mi] = *(const bf16x8*)&As[(wr * 64 + mi * 16 + lr) * 32 + lk];
        for (int ni = 0; ni < 4; ++ni)
            b[ni] = *(const bf16x8*)&Bs[(wc * 64 + ni * 16 + lr) * 32 + lk];
        for (int mi = 0; mi < 4; ++mi)
            for (int ni = 0; ni < 4; ++ni)
                acc[mi][ni] = __builtin_amdgcn_mfma_f32_16x16x32_bf16(
                    a[mi], b[ni], acc[mi][ni], 0, 0, 0);
        __syncthreads();
    }

    int lq = lane >> 4;
    for (int mi = 0; mi < 4; ++mi)
        for (int ni = 0; ni < 4; ++ni) {
            int col = n0 + wc * 64 + ni * 16 + lr;
            float bv = (MODE == 1) ? bias[col] : 0.0f;
            for (int r = 0; r < 4; ++r) {
                int row = m0 + wr * 64 + mi * 16 + lq * 4 + r;
                if (row < M) {
                    if (MODE == 0)
                        ((u16*)Cv)[(size_t)row * N + col] = f2bf(acc[mi][ni][r]);
                    else
                        ((float*)Cv)[(size_t)row * N + col] = acc[mi][ni][r] + bv;
                }
            }
        }
}

// ---------------- bos row: attn_out[b*4097][:] = v[b, n=0, :] --------------
__global__ __launch_bounds__(256) void bos_copy(
    const u16* __restrict__ qkv, u16* __restrict__ attn_out) {
    int b = blockIdx.x;
    int c = blockIdx.y * 256 + threadIdx.x;  // 0..1023
    attn_out[(size_t)b * 4097 * 1024 + c] =
        qkv[(size_t)b * 4097 * 3072 + 2048 + c];
}

// P-LDS swizzle: layout [j 0..63][i 0..15][h 0..15] bf16, byte = j*512+i*32+2h,
// XOR 3 bank-bits (byte 4..6) with a (j,i)-hash. b128-safe (bits >= 4), and
// h0..7 / h8..15 16B-blocks stay contiguous (hash independent of h).
__device__ __forceinline__ int pswz(int j, int i, int h) {
    int byte = j * 512 + i * 32 + h * 2;
    int sw = ((j & 7) ^ ((j >> 3) & 7) ^ ((i >> 2) & 3)) & 7;
    return byte ^ (sw << 4);
}

// ---------------- fused windowed attention + talking-heads -----------------
// one WG (4 waves) per (x, b). q-token i of tile x: t = 1 + x*16 + i.
// window j=0 -> bos, j=1..48 -> t = 1 + (x*16 - 32 + (j-1)).
// causal mask j <= i+33  =>  j >= 49 always masked, pad to 64 with zeros.
__global__ __launch_bounds__(256) void attn_kernel(
    const u16* __restrict__ qkv, const float* __restrict__ w_th,
    u16* __restrict__ attn_out) {
    __shared__ u16 P[64 * 16 * 16];   // 32 KB, swizzled [j][i][h]
    // per-wave V subtiles: [dblk 0..3][32 j][16 d] row-major 512B subtiles,
    // staged linearly by gld_lds16 (dest = base + lane*16B).
    __shared__ u16 vt[4][2048];       // 4 KB per wave
    __shared__ float wth_s[256];

    int tid = threadIdx.x;
    int wid = tid >> 6, lane = tid & 63;
    int x = blockIdx.x;                        // 0..255
    int b = blockIdx.y;                        // 0..3
    size_t base = (size_t)b * 4097 * 3072;
    int lr = lane & 15;
    int lq = lane >> 4;
    int lk8 = lq * 8;

    wth_s[tid] = w_th[tid];

    // ---- phase 1: per-head QK^T + mask + softmax -> P ----------------------
    for (int hh = 0; hh < 4; ++hh) {
        int h = wid * 4 + hh;
        const u16* qp = qkv + base + (size_t)(1 + x * 16 + lr) * 3072 + h * 64;
        bf16x8 aq0 = *(const bf16x8*)(qp + lk8);
        bf16x8 aq1 = *(const bf16x8*)(qp + 32 + lk8);
        f32x4 acc[4];
        #pragma unroll
        for (int jt = 0; jt < 4; ++jt) {
            int j = jt * 16 + lr;
            int tpos = x * 16 - 32 + (j - 1);
            int t = (j > 0 && tpos >= 0 && tpos < 4096) ? tpos + 1 : 0;
            const u16* kp = qkv + base + (size_t)t * 3072 + 1024 + h * 64;
            bf16x8 bk0 = *(const bf16x8*)(kp + lk8);
            bf16x8 bk1 = *(const bf16x8*)(kp + 32 + lk8);
            f32x4 c = {};
            c = __builtin_amdgcn_mfma_f32_16x16x32_bf16(aq0, bk0, c, 0, 0, 0);
            c = __builtin_amdgcn_mfma_f32_16x16x32_bf16(aq1, bk1, c, 0, 0, 0);
            acc[jt] = c;
        }
        // mask + softmax over j (16 lanes x 4 tiles hold the j axis)
        float m[4], s[4], p[4][4];
        #pragma unroll
        for (int r = 0; r < 4; ++r) m[r] = -3.0e38f;
        #pragma unroll
        for (int jt = 0; jt < 4; ++jt) {
            int j = jt * 16 + lr;
            int tpos = x * 16 - 32 + (j - 1);
            bool jvalid = (j == 0) || (tpos >= 0);
            #pragma unroll
            for (int r = 0; r < 4; ++r) {
                int i = lq * 4 + r;
                bool keep = jvalid && (j == 0 || j <= i + 33);
                float v = keep ? acc[jt][r] * 0.125f : -3.0e38f;
                p[jt][r] = v;
                m[r] = fmaxf(m[r], v);
            }
        }
        #pragma unroll
        for (int r = 0; r < 4; ++r) {
            float v = m[r];
            v = fmaxf(v, __shfl_xor(v, 1));
            v = fmaxf(v, __shfl_xor(v, 2));
            v = fmaxf(v, __shfl_xor(v, 4));
            v = fmaxf(v, __shfl_xor(v, 8));
            m[r] = v; s[r] = 0.0f;
        }
        #pragma unroll
        for (int jt = 0; jt < 4; ++jt)
            #pragma unroll
            for (int r = 0; r < 4; ++r) {
                float e = __expf(p[jt][r] - m[r]);
                p[jt][r] = e; s[r] += e;
            }
        #pragma unroll
        for (int r = 0; r < 4; ++r) {
            float v = s[r];
            v += __shfl_xor(v, 1); v += __shfl_xor(v, 2);
            v += __shfl_xor(v, 4); v += __shfl_xor(v, 8);
            s[r] = 1.0f / v;
        }
        #pragma unroll
        for (int jt = 0; jt < 4; ++jt) {
            int j = jt * 16 + lr;
            #pragma unroll
            for (int r = 0; r < 4; ++r) {
                int i = lq * 4 + r;
                *(u16*)((char*)P + pswz(j, i, h)) = f2bf(p[jt][r] * s[r]);
            }
        }
    }
    __syncthreads();

    // ---- phase 2: per-head head-mix (g) + PV MFMA --------------------------
    const u16* vtw = &vt[wid][0];
    // staging lane decomposition: lane = jloc*2 + dh
    int jloc = lane >> 1, dh = lane & 1;
    for (int gg = 0; gg < 4; ++gg) {
        int g = wid * 4 + gg;
        float wth[16];
        #pragma unroll
        for (int h2 = 0; h2 < 16; ++h2) wth[h2] = wth_s[g * 16 + h2];
        f32x4 oacc[4] = {};
        #pragma unroll
        for (int kk = 0; kk < 2; ++kk) {
            // stage V chunk j = kk*32..+31, head g: 4 wave-wide async loads.
            // pass w writes subtile dblk=w: element jloc*16 + dh*8 + dd holds
            // V[kk*32+jloc][w*16 + dh*8 + dd]. LDS dest = base + lane*16B.
            {
                int jg = kk * 32 + jloc;
                int tpos = x * 16 - 32 + (jg - 1);
                int t = (jg > 0 && tpos >= 0 && tpos < 4096) ? tpos + 1 : 0;
                const u16* src = qkv + base + (size_t)t * 3072 + 2048 + g * 64
                               + dh * 8;
                #pragma unroll
                for (int w = 0; w < 4; ++w)
                    gld_lds16(src + w * 16, &vt[wid][w * 512 + lane * 8]);
            }
            // mix heads -> A-frag (hides the staging latency under VALU).
            // P[j] for j in [49,63] is stored zero, so no guards needed.
            bf16x8 av;
            #pragma unroll
            for (int e = 0; e < 8; ++e) {
                int j = kk * 32 + lk8 + e;
                bf16x8 v0 = *(const bf16x8*)((const char*)P + pswz(j, lr, 0));
                bf16x8 v1 = *(const bf16x8*)((const char*)P + pswz(j, lr, 8));
                float s0 = 0.0f, s1 = 0.0f;
                #pragma unroll
                for (int h2 = 0; h2 < 8; ++h2) {
                    s0 += wth[h2]     * bf2f((u16)v0[h2]);
                    s1 += wth[h2 + 8] * bf2f((u16)v1[h2]);
                }
                av[e] = (short)f2bf(s0 + s1);
            }
            asm volatile("s_waitcnt vmcnt(0)" ::: "memory");
            // B-frags: plain scalar column gathers from row-major subtiles.
            // bv[e] = V[kk*32 + lq*8 + e][dt*16 + lr]  (compiler-tracked
            // ds_read_u16; lgkmcnt handled by normal dependency tracking).
            #pragma unroll
            for (int dt = 0; dt < 4; ++dt) {
                bf16x8 bv;
                #pragma unroll
                for (int e = 0; e < 8; ++e)
                    bv[e] = (short)vtw[dt * 512 + (lk8 + e) * 16 + lr];
                oacc[dt] = __builtin_amdgcn_mfma_f32_16x16x32_bf16(
                    av, bv, oacc[dt], 0, 0, 0);
            }
        }
        #pragma unroll
        for (int dt = 0; dt < 4; ++dt) {
            int col = g * 64 + dt * 16 + lr;
            #pragma unroll
            for (int r = 0; r < 4; ++r) {
                int i = lq * 4 + r;
                size_t row = (size_t)b * 4097 + 1 + (size_t)x * 16 + i;
                attn_out[row * 1024 + col] = f2bf(oacc[dt][r]);
            }
        }
    }
}

// ---------------------------------------------------------------------------
extern "C" void kernel_launch(void* const* d_in, const int* in_sizes, int n_in,
                              void* d_out, int out_size, void* d_ws, size_t ws_size,
                              hipStream_t stream) {
    const float* x     = (const float*)d_in[0];  // (4,4097,1024) f32
    const float* w_qkv = (const float*)d_in[1];  // (1024,3072)  f32
    const float* w_out = (const float*)d_in[2];  // (1024,1024)  f32
    const float* b_out = (const float*)d_in[3];  // (1024,)      f32
    const float* w_th  = (const float*)d_in[4];  // (16,16)      f32
    float* out = (float*)d_out;                  // (4,4097,1024) f32

    const int M = 4 * 4097;  // 16388
    u16* qkv      = (u16*)d_ws;                       // M x 3072      bf16
    u16* wqkvT    = qkv + (size_t)M * 3072;           // 3072 x 1024   bf16
    u16* woutT    = wqkvT + (size_t)3072 * 1024;      // 1024 x 1024   bf16
    u16* xb       = woutT + (size_t)1024 * 1024;      // M x 1024      bf16
    u16* attn_out = xb;  // aliases xb: xb dead after GEMM1 (stream-ordered)

    transpose_cvt<<<dim3(96, 32), 256, 0, stream>>>(w_qkv, wqkvT, 1024, 3072);
    transpose_cvt<<<dim3(32, 32), 256, 0, stream>>>(w_out, woutT, 1024, 1024);

    size_t total4 = (size_t)M * 1024 / 4;  // 4,195,328 float4s
    cvt_rows<<<(int)((total4 + 255) / 256), 256, 0, stream>>>(x, xb, total4);

    int mt = (M + 127) / 128;  // 129
    gemm_bt<0><<<dim3(mt, 3072 / 128), 256, 0, stream>>>(
        xb, wqkvT, nullptr, qkv, M, 3072, 1024);

    bos_copy<<<dim3(4, 4), 256, 0, stream>>>(qkv, attn_out);
    attn_kernel<<<dim3(256, 4), 256, 0, stream>>>(qkv, w_th, attn_out);

    gemm_bt<1><<<dim3(mt, 1024 / 128), 256, 0, stream>>>(
        attn_out, woutT, b_out, out, M, 1024, 1024);
}

// Round 6
// 305.838 us; speedup vs baseline: 2.4825x; 1.0656x over previous
//
#include <hip/hip_runtime.h>
#include <stdint.h>

typedef unsigned short u16;
typedef unsigned int u32;
typedef __attribute__((ext_vector_type(8))) short bf16x8;
typedef __attribute__((ext_vector_type(4))) float f32x4;

__device__ __forceinline__ float bf2f(u16 u) {
    union { u32 i; float f; } v; v.i = ((u32)u) << 16; return v.f;
}
__device__ __forceinline__ u16 f2bf(float f) {
    union { float f; u32 i; } v; v.f = f;
    u32 x = v.i;
    u32 r = (x + 0x7FFFu + ((x >> 16) & 1u)) >> 16;  // RNE
    return (u16)r;
}

__device__ __forceinline__ void gld_lds16(const void* g, void* l) {
    __builtin_amdgcn_global_load_lds(
        (const __attribute__((address_space(1))) void*)g,
        (__attribute__((address_space(3))) void*)l, 16, 0, 0);
}

// ---------------- f32 -> bf16 row convert (vectorized) ---------------------
__global__ __launch_bounds__(256) void cvt_rows(
    const float* __restrict__ src, u16* __restrict__ dst, size_t total4) {
    size_t i = (size_t)blockIdx.x * 256 + threadIdx.x;  // one float4 per thread
    if (i >= total4) return;
    const float4 v = ((const float4*)src)[i];
    u16 o[4] = {f2bf(v.x), f2bf(v.y), f2bf(v.z), f2bf(v.w)};
    *(unsigned long long*)(dst + i * 4) = *(unsigned long long*)o;
}

// ---------------- transpose+convert: dst_bf16[c][r] = src_f32[r][c] --------
__global__ __launch_bounds__(256) void transpose_cvt(
    const float* __restrict__ src, u16* __restrict__ dst, int R, int C) {
    __shared__ float tile[32][33];
    int c0 = blockIdx.x * 32, r0 = blockIdx.y * 32;
    int tx = threadIdx.x & 31, ty = threadIdx.x >> 5;  // ty 0..7
    for (int rr = ty; rr < 32; rr += 8)
        tile[rr][tx] = src[(size_t)(r0 + rr) * C + c0 + tx];
    __syncthreads();
    for (int rr = ty; rr < 32; rr += 8)
        dst[(size_t)(c0 + rr) * R + r0 + tx] = f2bf(tile[tx][rr]);
}

// ---------------- GEMM v2: 256^2 tile, BK=64, 8 waves, counted-vmcnt -------
// C[M][N] = A[M][K] * Bt[N][K]^T. MODE 0: bf16 out. MODE 1: f32 out + bias.
// Schedule (race-free by construction):
//   prologue: STAGE(K0->buf0), STAGE(K1->buf1)
//   iter t:  vmcnt(8) [K_t landed, K_{t+1} in flight] ; s_barrier ;
//            fragread+MFMA (lgkm drained by compiler before each MFMA) ;
//            s_barrier ; STAGE(K_{t+2} -> buf t&1)
// LDS swizzle: 16B chunk c stored at c ^ e(row), e(row)=(row&7)^((row>>3)&1);
// write side via pre-swizzled GLOBAL source (gld_lds dest stays linear, G21),
// read side applies the same involution.
template <int MODE>
__global__ __launch_bounds__(512) void gemm_bt2(
    const u16* __restrict__ A, const u16* __restrict__ Bt,
    const float* __restrict__ bias, void* __restrict__ Cv,
    int M, int N, int K) {
    __shared__ u16 lds[2][2][256 * 64];   // [buf][A/B][row*64 + el]  128 KB
    int tid = threadIdx.x;
    int wid = tid >> 6, lane = tid & 63;
    int lr = lane & 15, lq = lane >> 4;
    int wr = wid >> 2, wc = wid & 3;      // 2 x 4 wave grid
    int m0 = blockIdx.x * 256, n0 = blockIdx.y * 256;
    int NT = K >> 6;                      // K-tiles of 64

    f32x4 acc[8][4] = {};

    #define STAGE(t, buf)                                                     \
    do {                                                                      \
        int k0 = (t) << 6;                                                    \
        _Pragma("unroll")                                                     \
        for (int w = 0; w < 4; ++w) {                                         \
            int g = w * 512 + tid;                                            \
            int row = g >> 3;                                                 \
            int cdat = (g & 7) ^ ((row & 7) ^ ((row >> 3) & 1));              \
            int gm = m0 + row; if (gm >= M) gm = M - 1;                       \
            gld_lds16(A + (size_t)gm * K + k0 + cdat * 8,                     \
                      &lds[buf][0][g * 8]);                                   \
        }                                                                     \
        _Pragma("unroll")                                                     \
        for (int w = 0; w < 4; ++w) {                                         \
            int g = w * 512 + tid;                                            \
            int row = g >> 3;                                                 \
            int cdat = (g & 7) ^ ((row & 7) ^ ((row >> 3) & 1));              \
            int gn = n0 + row;                                                \
            gld_lds16(Bt + (size_t)gn * K + k0 + cdat * 8,                    \
                      &lds[buf][1][g * 8]);                                   \
        }                                                                     \
    } while (0)

    STAGE(0, 0);
    STAGE(1, 1);

    for (int t = 0; t < NT; ++t) {
        int buf = t & 1;
        if (t + 1 < NT) asm volatile("s_waitcnt vmcnt(8)" ::: "memory");
        else            asm volatile("s_waitcnt vmcnt(0)" ::: "memory");
        asm volatile("s_barrier" ::: "memory");
        const u16* Ab = &lds[buf][0][0];
        const u16* Bb = &lds[buf][1][0];
        #pragma unroll
        for (int ks = 0; ks < 2; ++ks) {
            int c = ks * 4 + lq;
            bf16x8 a[8], b[4];
            #pragma unroll
            for (int mi = 0; mi < 8; ++mi) {
                int r = wr * 128 + mi * 16 + lr;
                int cs = c ^ ((r & 7) ^ ((r >> 3) & 1));
                a[mi] = *(const bf16x8*)&Ab[r * 64 + cs * 8];
            }
            #pragma unroll
            for (int ni = 0; ni < 4; ++ni) {
                int r = wc * 64 + ni * 16 + lr;
                int cs = c ^ ((r & 7) ^ ((r >> 3) & 1));
                b[ni] = *(const bf16x8*)&Bb[r * 64 + cs * 8];
            }
            __builtin_amdgcn_s_setprio(1);
            #pragma unroll
            for (int mi = 0; mi < 8; ++mi)
                #pragma unroll
                for (int ni = 0; ni < 4; ++ni)
                    acc[mi][ni] = __builtin_amdgcn_mfma_f32_16x16x32_bf16(
                        a[mi], b[ni], acc[mi][ni], 0, 0, 0);
            __builtin_amdgcn_s_setprio(0);
        }
        asm volatile("s_barrier" ::: "memory");
        if (t + 2 < NT) STAGE(t + 2, buf);
    }
    #undef STAGE

    // epilogue
    #pragma unroll
    for (int mi = 0; mi < 8; ++mi)
        #pragma unroll
        for (int ni = 0; ni < 4; ++ni) {
            int col = n0 + wc * 64 + ni * 16 + lr;
            float bv = (MODE == 1) ? bias[col] : 0.0f;
            #pragma unroll
            for (int r = 0; r < 4; ++r) {
                int row = m0 + wr * 128 + mi * 16 + lq * 4 + r;
                if (row < M) {
                    if (MODE == 0)
                        ((u16*)Cv)[(size_t)row * N + col] = f2bf(acc[mi][ni][r]);
                    else
                        ((float*)Cv)[(size_t)row * N + col] = acc[mi][ni][r] + bv;
                }
            }
        }
}

// ---------------- bos row: attn_out[b*4097][:] = v[b, n=0, :] --------------
__global__ __launch_bounds__(256) void bos_copy(
    const u16* __restrict__ qkv, u16* __restrict__ attn_out) {
    int b = blockIdx.x;
    int c = blockIdx.y * 256 + threadIdx.x;  // 0..1023
    attn_out[(size_t)b * 4097 * 1024 + c] =
        qkv[(size_t)b * 4097 * 3072 + 2048 + c];
}

// P-LDS swizzle: layout [j 0..63][i 0..15][h 0..15] bf16, byte = j*512+i*32+2h,
// XOR 3 bank-bits (byte 4..6) with a (j,i)-hash. b128-safe (bits >= 4), and
// h0..7 / h8..15 16B-blocks stay contiguous (hash independent of h).
__device__ __forceinline__ int pswz(int j, int i, int h) {
    int byte = j * 512 + i * 32 + h * 2;
    int sw = ((j & 7) ^ ((j >> 3) & 7) ^ ((i >> 2) & 3)) & 7;
    return byte ^ (sw << 4);
}

// ---------------- fused windowed attention + talking-heads -----------------
// one WG (4 waves) per (x, b). q-token i of tile x: t = 1 + x*16 + i.
// window j=0 -> bos, j=1..48 -> t = 1 + (x*16 - 32 + (j-1)).
// causal mask j <= i+33  =>  j >= 49 always masked, pad to 64 with zeros.
__global__ __launch_bounds__(256) void attn_kernel(
    const u16* __restrict__ qkv, const float* __restrict__ w_th,
    u16* __restrict__ attn_out) {
    __shared__ u16 P[64 * 16 * 16];   // 32 KB, swizzled [j][i][h]
    __shared__ u16 vt[4][2048];       // 4 KB/wave: [4 dblk][32 j][16 d]
    __shared__ float wth_s[256];

    int tid = threadIdx.x;
    int wid = tid >> 6, lane = tid & 63;
    int x = blockIdx.x;                        // 0..255
    int b = blockIdx.y;                        // 0..3
    size_t base = (size_t)b * 4097 * 3072;
    int lr = lane & 15;
    int lq = lane >> 4;
    int lk8 = lq * 8;

    wth_s[tid] = w_th[tid];

    // ---- phase 1: per-head QK^T + mask + softmax -> P ----------------------
    for (int hh = 0; hh < 4; ++hh) {
        int h = wid * 4 + hh;
        const u16* qp = qkv + base + (size_t)(1 + x * 16 + lr) * 3072 + h * 64;
        bf16x8 aq0 = *(const bf16x8*)(qp + lk8);
        bf16x8 aq1 = *(const bf16x8*)(qp + 32 + lk8);
        f32x4 acc[4];
        #pragma unroll
        for (int jt = 0; jt < 4; ++jt) {
            int j = jt * 16 + lr;
            int tpos = x * 16 - 32 + (j - 1);
            int t = (j > 0 && tpos >= 0 && tpos < 4096) ? tpos + 1 : 0;
            const u16* kp = qkv + base + (size_t)t * 3072 + 1024 + h * 64;
            bf16x8 bk0 = *(const bf16x8*)(kp + lk8);
            bf16x8 bk1 = *(const bf16x8*)(kp + 32 + lk8);
            f32x4 c = {};
            c = __builtin_amdgcn_mfma_f32_16x16x32_bf16(aq0, bk0, c, 0, 0, 0);
            c = __builtin_amdgcn_mfma_f32_16x16x32_bf16(aq1, bk1, c, 0, 0, 0);
            acc[jt] = c;
        }
        // mask + softmax over j (16 lanes x 4 tiles hold the j axis)
        float m[4], s[4], p[4][4];
        #pragma unroll
        for (int r = 0; r < 4; ++r) m[r] = -3.0e38f;
        #pragma unroll
        for (int jt = 0; jt < 4; ++jt) {
            int j = jt * 16 + lr;
            int tpos = x * 16 - 32 + (j - 1);
            bool jvalid = (j == 0) || (tpos >= 0);
            #pragma unroll
            for (int r = 0; r < 4; ++r) {
                int i = lq * 4 + r;
                bool keep = jvalid && (j == 0 || j <= i + 33);
                float v = keep ? acc[jt][r] * 0.125f : -3.0e38f;
                p[jt][r] = v;
                m[r] = fmaxf(m[r], v);
            }
        }
        #pragma unroll
        for (int r = 0; r < 4; ++r) {
            float v = m[r];
            v = fmaxf(v, __shfl_xor(v, 1));
            v = fmaxf(v, __shfl_xor(v, 2));
            v = fmaxf(v, __shfl_xor(v, 4));
            v = fmaxf(v, __shfl_xor(v, 8));
            m[r] = v; s[r] = 0.0f;
        }
        #pragma unroll
        for (int jt = 0; jt < 4; ++jt)
            #pragma unroll
            for (int r = 0; r < 4; ++r) {
                float e = __expf(p[jt][r] - m[r]);
                p[jt][r] = e; s[r] += e;
            }
        #pragma unroll
        for (int r = 0; r < 4; ++r) {
            float v = s[r];
            v += __shfl_xor(v, 1); v += __shfl_xor(v, 2);
            v += __shfl_xor(v, 4); v += __shfl_xor(v, 8);
            s[r] = 1.0f / v;
        }
        #pragma unroll
        for (int jt = 0; jt < 4; ++jt) {
            int j = jt * 16 + lr;
            #pragma unroll
            for (int r = 0; r < 4; ++r) {
                int i = lq * 4 + r;
                *(u16*)((char*)P + pswz(j, i, h)) = f2bf(p[jt][r] * s[r]);
            }
        }
    }
    __syncthreads();

    // ---- phase 2: per-head head-mix (g) + PV MFMA --------------------------
    const u16* vtw = &vt[wid][0];
    int jloc = lane >> 1, dh = lane & 1;
    for (int gg = 0; gg < 4; ++gg) {
        int g = wid * 4 + gg;
        float wth[16];
        #pragma unroll
        for (int h2 = 0; h2 < 16; ++h2) wth[h2] = wth_s[g * 16 + h2];
        f32x4 oacc[4] = {};
        #pragma unroll
        for (int kk = 0; kk < 2; ++kk) {
            {
                int jg = kk * 32 + jloc;
                int tpos = x * 16 - 32 + (jg - 1);
                int t = (jg > 0 && tpos >= 0 && tpos < 4096) ? tpos + 1 : 0;
                const u16* src = qkv + base + (size_t)t * 3072 + 2048 + g * 64
                               + dh * 8;
                #pragma unroll
                for (int w = 0; w < 4; ++w)
                    gld_lds16(src + w * 16, &vt[wid][w * 512 + lane * 8]);
            }
            // mix heads -> A-frag (hides the staging latency under VALU).
            bf16x8 av;
            #pragma unroll
            for (int e = 0; e < 8; ++e) {
                int j = kk * 32 + lk8 + e;
                bf16x8 v0 = *(const bf16x8*)((const char*)P + pswz(j, lr, 0));
                bf16x8 v1 = *(const bf16x8*)((const char*)P + pswz(j, lr, 8));
                float s0 = 0.0f, s1 = 0.0f;
                #pragma unroll
                for (int h2 = 0; h2 < 8; ++h2) {
                    s0 += wth[h2]     * bf2f((u16)v0[h2]);
                    s1 += wth[h2 + 8] * bf2f((u16)v1[h2]);
                }
                av[e] = (short)f2bf(s0 + s1);
            }
            asm volatile("s_waitcnt vmcnt(0)" ::: "memory");
            // B-frags: scalar column gathers from row-major subtiles.
            #pragma unroll
            for (int dt = 0; dt < 4; ++dt) {
                bf16x8 bv;
                #pragma unroll
                for (int e = 0; e < 8; ++e)
                    bv[e] = (short)vtw[dt * 512 + (lk8 + e) * 16 + lr];
                oacc[dt] = __builtin_amdgcn_mfma_f32_16x16x32_bf16(
                    av, bv, oacc[dt], 0, 0, 0);
            }
        }
        #pragma unroll
        for (int dt = 0; dt < 4; ++dt) {
            int col = g * 64 + dt * 16 + lr;
            #pragma unroll
            for (int r = 0; r < 4; ++r) {
                int i = lq * 4 + r;
                size_t row = (size_t)b * 4097 + 1 + (size_t)x * 16 + i;
                attn_out[row * 1024 + col] = f2bf(oacc[dt][r]);
            }
        }
    }
}

// ---------------------------------------------------------------------------
extern "C" void kernel_launch(void* const* d_in, const int* in_sizes, int n_in,
                              void* d_out, int out_size, void* d_ws, size_t ws_size,
                              hipStream_t stream) {
    const float* x     = (const float*)d_in[0];  // (4,4097,1024) f32
    const float* w_qkv = (const float*)d_in[1];  // (1024,3072)  f32
    const float* w_out = (const float*)d_in[2];  // (1024,1024)  f32
    const float* b_out = (const float*)d_in[3];  // (1024,)      f32
    const float* w_th  = (const float*)d_in[4];  // (16,16)      f32
    float* out = (float*)d_out;                  // (4,4097,1024) f32

    const int M = 4 * 4097;  // 16388
    u16* qkv      = (u16*)d_ws;                       // M x 3072      bf16
    u16* wqkvT    = qkv + (size_t)M * 3072;           // 3072 x 1024   bf16
    u16* woutT    = wqkvT + (size_t)3072 * 1024;      // 1024 x 1024   bf16
    u16* xb       = woutT + (size_t)1024 * 1024;      // M x 1024      bf16
    u16* attn_out = xb;  // aliases xb: xb dead after GEMM1 (stream-ordered)

    transpose_cvt<<<dim3(96, 32), 256, 0, stream>>>(w_qkv, wqkvT, 1024, 3072);
    transpose_cvt<<<dim3(32, 32), 256, 0, stream>>>(w_out, woutT, 1024, 1024);

    size_t total4 = (size_t)M * 1024 / 4;  // 4,195,328 float4s
    cvt_rows<<<(int)((total4 + 255) / 256), 256, 0, stream>>>(x, xb, total4);

    int mt = (M + 255) / 256;  // 65
    gemm_bt2<0><<<dim3(mt, 3072 / 256), 512, 0, stream>>>(
        xb, wqkvT, nullptr, qkv, M, 3072, 1024);

    bos_copy<<<dim3(4, 4), 256, 0, stream>>>(qkv, attn_out);
    attn_kernel<<<dim3(256, 4), 256, 0, stream>>>(qkv, w_th, attn_out);

    gemm_bt2<1><<<dim3(mt, 1024 / 256), 512, 0, stream>>>(
        attn_out, woutT, b_out, out, M, 1024, 1024);
}